// Round 2
// baseline (607.941 us; speedup 1.0000x reference)
//
#include <hip/hip_runtime.h>
#include <math.h>

// Problem constants
#define B_    32
#define H_IN  161
#define W_IN  1024
#define C1_   32
#define H1_   81
#define W1_   512
#define C2_   32
#define H2_   41
#define W2_   512

#define OUT_X_SZ ((size_t)B_ * C2_ * H2_ * W2_)            // 21,495,808

// ws byte offsets (all 16B-aligned)
#define WF2_B    0u            // 236544 bf16 (conv2 weights, A-frag order)
#define WF1_B    473088u       // 41*512 bf16 (conv1 weights, A-frag order, k 11->16 zero-pad)
#define SCSH_B   515072u       // 128 fp32
#define LENS1_B  515584u       // 32 int
#define XG_B     515712u       // 32*81*512*32 bf16 = 84,934,656 B

#define WF2_N    236544
#define WF1_N    20992         // 41 * 512

typedef __bf16 v8bf __attribute__((ext_vector_type(8)));
typedef float v16f __attribute__((ext_vector_type(16)));

static __device__ __forceinline__ unsigned short f2bf(float f) {
    unsigned int u = __float_as_uint(f);
    unsigned int r = (u + 0x7fffu + ((u >> 16) & 1u)) >> 16;
    return (unsigned short)r;
}

// ---------------------------------------------------------------------------
// Prep: pack conv1+conv2 weights into MFMA A-fragment lane order (bf16),
// fold BN, compute lens.
// ---------------------------------------------------------------------------
__global__ void prep_kernel(const float* __restrict__ w1, const float* __restrict__ b1,
                            const float* __restrict__ g1, const float* __restrict__ be1,
                            const float* __restrict__ m1, const float* __restrict__ v1,
                            const float* __restrict__ w2, const float* __restrict__ b2,
                            const float* __restrict__ g2, const float* __restrict__ be2,
                            const float* __restrict__ m2, const float* __restrict__ v2,
                            const int* __restrict__ lens,
                            unsigned short* __restrict__ wf1, unsigned short* __restrict__ wf2,
                            float* __restrict__ scsh, int* __restrict__ lens1,
                            float* __restrict__ out_lens)
{
    const int i = blockIdx.x * blockDim.x + threadIdx.x;
    const int stride = gridDim.x * blockDim.x;

    // wf2: frag f=(kh*11+kw)*2+ch, lane l, elem j <- w2[oc=l&31][c=ch*16+(l>>5)*8+j][kh][kw]
    for (int idx = i; idx < WF2_N; idx += stride) {
        int j  = idx & 7;
        int l  = (idx >> 3) & 63;
        int f  = idx >> 9;
        int ch = f & 1;
        int kwkh = f >> 1;
        int kw = kwkh % 11;
        int kh = kwkh / 11;
        int oc = l & 31;
        int c  = ch * 16 + ((l >> 5) << 3) + j;
        wf2[idx] = f2bf(w2[((oc * 32 + c) * 21 + kh) * 11 + kw]);
    }
    // wf1: frag kh, lane l, elem j <- w1[oc=l&31][kh][k=(l>>5)*8+j], zero for k>=11
    for (int idx = i; idx < WF1_N; idx += stride) {
        int j  = idx & 7;
        int l  = (idx >> 3) & 63;
        int kh = idx >> 9;
        int k  = ((l >> 5) << 3) + j;
        int oc = l & 31;
        wf1[idx] = (k < 11) ? f2bf(w1[oc * 451 + kh * 11 + k]) : (unsigned short)0;
    }
    if (i < 32) {
        float s1 = g1[i] / sqrtf(v1[i] + 1e-5f);
        scsh[i]      = s1;
        scsh[32 + i] = b1[i] * s1 + be1[i] - m1[i] * s1;
        float s2 = g2[i] / sqrtf(v2[i] + 1e-5f);
        scsh[64 + i] = s2;
        scsh[96 + i] = b2[i] * s2 + be2[i] - m2[i] * s2;
        int l1 = (lens[i] - 1) / 2 + 1;
        if (l1 > W1_) l1 = W1_;
        lens1[i] = l1;
        out_lens[i] = (float)l1;
    }
}

// ---------------------------------------------------------------------------
// Conv1 via bf16 MFMA implicit GEMM (unchanged this round).
// ---------------------------------------------------------------------------
__global__ __launch_bounds__(256) void conv1_mfma(
    const float* __restrict__ x,             // [32][1][161][1024]
    const unsigned short* __restrict__ wf1,  // frag-ordered
    const float* __restrict__ scsh,
    const int* __restrict__ lens1,
    unsigned short* __restrict__ xg)         // [32][81][512][32] bf16
{
    const int t    = threadIdx.x;
    const int lane = t & 63;
    const int l31  = lane & 31;
    const int lhi  = lane >> 5;
    const int wv   = t >> 6;
    const int w0   = blockIdx.x * 256;
    const int h    = blockIdx.y;
    const int b    = blockIdx.z;

    __shared__ unsigned int srow[2][264];    // 264 uints = 528 bf16 per buffer

    v16f acc0, acc1;
#pragma unroll
    for (int i = 0; i < 16; ++i) { acc0[i] = 0.f; acc1[i] = 0.f; }

    const int r0 = 2 * h - 20;
    const int cb = 2 * w0 - 5;               // global col of staged elem 0
    const float* xb = x + (size_t)b * (H_IN * W_IN);

    // dword read base for B frags: dw = wloc + 4*lhi
    const int dwbase = wv * 64 + l31 + 4 * lhi;

    // ---- prologue: stage row r0 into buffer 0 ----
    {
        float a0 = 0.f, a1 = 0.f, c0v = 0.f, c1v = 0.f;
        if (r0 >= 0 && r0 < H_IN) {
            const float* src = xb + (size_t)r0 * W_IN;
            int c0 = cb + 2 * t;
            if ((unsigned)c0 < (unsigned)W_IN)       a0 = src[c0];
            if ((unsigned)(c0 + 1) < (unsigned)W_IN) a1 = src[c0 + 1];
            if (t < 7) {
                int c1 = cb + 2 * (256 + t);
                if ((unsigned)c1 < (unsigned)W_IN)       c0v = src[c1];
                if ((unsigned)(c1 + 1) < (unsigned)W_IN) c1v = src[c1 + 1];
            }
        }
        srow[0][t] = (unsigned int)f2bf(a0) | ((unsigned int)f2bf(a1) << 16);
        if (t < 7)
            srow[0][256 + t] = (unsigned int)f2bf(c0v) | ((unsigned int)f2bf(c1v) << 16);
    }
    __syncthreads();

    for (int kh = 0; kh < 41; ++kh) {
        const int p = kh & 1;
        const int rn = r0 + kh + 1;
        const bool rv = (kh < 40) && (rn >= 0) && (rn < H_IN);

        // issue next-row staging loads (hidden under MFMAs)
        float a0 = 0.f, a1 = 0.f, c0v = 0.f, c1v = 0.f;
        if (rv) {
            const float* src = xb + (size_t)rn * W_IN;
            int c0 = cb + 2 * t;
            if ((unsigned)c0 < (unsigned)W_IN)       a0 = src[c0];
            if ((unsigned)(c0 + 1) < (unsigned)W_IN) a1 = src[c0 + 1];
            if (t < 7) {
                int c1 = cb + 2 * (256 + t);
                if ((unsigned)c1 < (unsigned)W_IN)       c0v = src[c1];
                if ((unsigned)(c1 + 1) < (unsigned)W_IN) c1v = src[c1 + 1];
            }
        }

        // compute on buffer p
        const int r = r0 + kh;
        if (r >= 0 && r < H_IN) {
            uint4 a_u = *((const uint4*)wf1 + kh * 32 + lane);
            v8bf a = __builtin_bit_cast(v8bf, a_u);
            const unsigned int* bp = &srow[p][0];
            {
                int dw = dwbase;
                uint4 bu;
                bu.x = bp[dw]; bu.y = bp[dw + 1]; bu.z = bp[dw + 2]; bu.w = bp[dw + 3];
                v8bf bb = __builtin_bit_cast(v8bf, bu);
                acc0 = __builtin_amdgcn_mfma_f32_32x32x16_bf16(a, bb, acc0, 0, 0, 0);
            }
            {
                int dw = dwbase + 32;
                uint4 bu;
                bu.x = bp[dw]; bu.y = bp[dw + 1]; bu.z = bp[dw + 2]; bu.w = bp[dw + 3];
                v8bf bb = __builtin_bit_cast(v8bf, bu);
                acc1 = __builtin_amdgcn_mfma_f32_32x32x16_bf16(a, bb, acc1, 0, 0, 0);
            }
        }

        // write staged row into buffer p^1
        if (rv) {
            srow[p ^ 1][t] = (unsigned int)f2bf(a0) | ((unsigned int)f2bf(a1) << 16);
            if (t < 7)
                srow[p ^ 1][256 + t] = (unsigned int)f2bf(c0v) | ((unsigned int)f2bf(c1v) << 16);
        }
        __syncthreads();
    }

    // ---- epilogue: BN + hardtanh + mask, write xg[b][h][w][c] bf16 ----
    const int l1 = lens1[b];
#pragma unroll
    for (int nt = 0; nt < 2; ++nt) {
        const int w = w0 + wv * 64 + nt * 32 + l31;
        const bool keep = (w < l1);
        unsigned short* dp = xg + (((size_t)b * H1_ + h) * W1_ + w) * 32;
#pragma unroll
        for (int rq = 0; rq < 4; ++rq) {
            unsigned int wd[2];
#pragma unroll
            for (int d = 0; d < 2; ++d) {
                int rg = rq * 4 + d * 2;
                int oc = 8 * rq + 4 * lhi + d * 2;
                float av0 = (nt == 0) ? acc0[rg]     : acc1[rg];
                float av1 = (nt == 0) ? acc0[rg + 1] : acc1[rg + 1];
                float v0 = fminf(fmaxf(fmaf(av0, scsh[oc],     scsh[32 + oc]), 0.f), 20.f);
                float v1 = fminf(fmaxf(fmaf(av1, scsh[oc + 1], scsh[33 + oc]), 0.f), 20.f);
                if (!keep) { v0 = 0.f; v1 = 0.f; }
                wd[d] = (unsigned int)f2bf(v0) | ((unsigned int)f2bf(v1) << 16);
            }
            uint2 u; u.x = wd[0]; u.y = wd[1];
            *(uint2*)(dp + 8 * rq + 4 * lhi) = u;
        }
    }
}

// ---------------------------------------------------------------------------
// Conv2 v4: h-pair x 4-mtile register-tiled implicit GEMM, reg-staged LDS.
// Block = (b, 256-w half, h-pair), 128 threads (2 waves), each wave owns
// 128 w (4 m-tiles of 32). Loop over input rows r; per (kw,ch): 4 input
// B-frags from LDS (XOR slot-swizzle), 2 weight A-frags from global/L1
// (kh0 = r+10-2h0, kh1 = kh0-2), 16 MFMAs. Input frag reused x2 (h-pair),
// weight frag reused x4 (m-tiles). Each xg row staged ONCE per block:
// global->reg (issued before MFMA cluster, latency hidden) -> ds_write_b128
// after (conv1's proven pattern; no global_load_lds).
//
// LDS: 2 buffers x 266 positions x 64 B = 34048 B. pos p holds w' =
// w0B + p - 5 (zero-filled when w' outside [0,512)). 16B slot s_g of a
// position is stored at slot s_g ^ ((pos>>1)&3)  (same involution on the
// read side; m-tile stride 2048 B = 32 pos preserves the swizzle phase).
// ---------------------------------------------------------------------------
#define C2BUF 17024            // 266 * 64 bytes per buffer

__global__ __launch_bounds__(128, 2) void conv2_mfma(
    const unsigned short* __restrict__ xg,   // [32][81][512][32] bf16
    const unsigned short* __restrict__ wf2,  // frag-ordered
    const float* __restrict__ scsh,
    const int* __restrict__ lens1,
    float* __restrict__ out)                 // [32][32][41][512] fp32
{
    const int t    = threadIdx.x;
    const int lane = t & 63;
    const int l31  = lane & 31;
    const int lhi  = lane >> 5;
    const int wid  = t >> 6;                 // 0..1

    // XCD-aware swizzle: grid 1344 = 8 * 168 (bijective); same-b blocks
    // cluster on one XCD so xg row re-reads hit that XCD's L2.
    const int id   = blockIdx.x;
    const int sid  = (id & 7) * 168 + (id >> 3);
    const int wblk = sid & 1;                // 256-w half
    const int bh   = sid >> 1;               // 0..671
    const int hp   = bh % 21;
    const int b    = bh / 21;
    const int h0   = hp << 1;
    const bool h1v = (h0 + 1) < 41;

    __shared__ __align__(16) char sbuf[2 * C2BUF];

    const int w0B = wblk << 8;               // 0 or 256
    const unsigned short* xb = xg + (size_t)b * (H1_ * W1_ * 32);

    // r-invariant staging decomposition: 1064 16B chunks over 128 threads,
    // 9 rounds (last partial: t < 40).
    int srcoff[9], ldsoff[9];
    bool vld[9];
#pragma unroll
    for (int i = 0; i < 9; ++i) {
        int k   = t + i * 128;
        int pos = k >> 2;
        int sg  = k & 3;
        int wp  = w0B + pos - 5;
        vld[i]    = (k < 1064) && (wp >= 0) && (wp < W1_);
        srcoff[i] = wp * 64 + sg * 16;
        ldsoff[i] = pos * 64 + ((sg ^ ((pos >> 1) & 3)) << 4);
    }

    const int rlo = max(0, 2 * h0 - 10);
    const int rhi = min(80, 2 * h0 + 12);

    v16f acc[2][4];
#pragma unroll
    for (int hh = 0; hh < 2; ++hh)
#pragma unroll
        for (int mt = 0; mt < 4; ++mt)
#pragma unroll
            for (int q = 0; q < 16; ++q) acc[hh][mt][q] = 0.f;

    uint4 g[9];

#define C2_STAGE_LOAD(ROW)                                                   \
    {                                                                        \
        const char* xrow = (const char*)(xb + (size_t)(ROW) * (W1_ * 32));   \
        _Pragma("unroll")                                                    \
        for (int i = 0; i < 9; ++i) {                                        \
            g[i].x = g[i].y = g[i].z = g[i].w = 0u;                          \
            if (vld[i]) g[i] = *(const uint4*)(xrow + srcoff[i]);            \
        }                                                                    \
    }

#define C2_STAGE_WRITE(PP)                                                   \
    {                                                                        \
        char* dst = sbuf + (PP) * C2BUF;                                     \
        _Pragma("unroll")                                                    \
        for (int i = 0; i < 8; ++i) *(uint4*)(dst + ldsoff[i]) = g[i];       \
        if (t < 40) *(uint4*)(dst + ldsoff[8]) = g[8];                       \
    }

    // prologue: stage row rlo into buffer 0
    C2_STAGE_LOAD(rlo);
    C2_STAGE_WRITE(0);
    __syncthreads();

    const uint4* wq = (const uint4*)wf2;
    const int pbase = (wid << 7) + l31;      // pos for mt=0, kw=0

    for (int r = rlo; r <= rhi; ++r) {
        const int p = (r - rlo) & 1;

        // issue next-row global loads (consumed after the MFMA cluster)
        if (r < rhi) C2_STAGE_LOAD(r + 1);

        const int kh0 = r + 10 - 2 * h0;     // >= 0 by rlo construction
        const int kh1 = kh0 - 2;
        const bool vh0 = (kh0 <= 20);
        const bool vh1 = h1v && (kh1 >= 0);  // kh1 <= 20 automatic
        const int f0 = kh0 * 22;
        const int f1 = kh1 * 22;
        const char* bb = sbuf + p * C2BUF;

        __builtin_amdgcn_s_setprio(1);
#pragma unroll
        for (int kw = 0; kw < 11; ++kw) {
            const int pos0 = pbase + kw;
            const int swz  = (pos0 >> 1) & 3;
            const int a0   = (pos0 << 6) + ((lhi ^ swz) << 4);   // ch=0
            const int a1   = a0 ^ 32;                            // ch=1
            uint4 b00 = *(const uint4*)(bb + a0);
            uint4 b01 = *(const uint4*)(bb + a0 + 2048);
            uint4 b02 = *(const uint4*)(bb + a0 + 4096);
            uint4 b03 = *(const uint4*)(bb + a0 + 6144);
            uint4 b10 = *(const uint4*)(bb + a1);
            uint4 b11 = *(const uint4*)(bb + a1 + 2048);
            uint4 b12 = *(const uint4*)(bb + a1 + 4096);
            uint4 b13 = *(const uint4*)(bb + a1 + 6144);
            if (vh0) {
                v8bf A0 = __builtin_bit_cast(v8bf, wq[(f0 + 2 * kw) * 64 + lane]);
                v8bf A1 = __builtin_bit_cast(v8bf, wq[(f0 + 2 * kw + 1) * 64 + lane]);
                acc[0][0] = __builtin_amdgcn_mfma_f32_32x32x16_bf16(A0, __builtin_bit_cast(v8bf, b00), acc[0][0], 0, 0, 0);
                acc[0][1] = __builtin_amdgcn_mfma_f32_32x32x16_bf16(A0, __builtin_bit_cast(v8bf, b01), acc[0][1], 0, 0, 0);
                acc[0][2] = __builtin_amdgcn_mfma_f32_32x32x16_bf16(A0, __builtin_bit_cast(v8bf, b02), acc[0][2], 0, 0, 0);
                acc[0][3] = __builtin_amdgcn_mfma_f32_32x32x16_bf16(A0, __builtin_bit_cast(v8bf, b03), acc[0][3], 0, 0, 0);
                acc[0][0] = __builtin_amdgcn_mfma_f32_32x32x16_bf16(A1, __builtin_bit_cast(v8bf, b10), acc[0][0], 0, 0, 0);
                acc[0][1] = __builtin_amdgcn_mfma_f32_32x32x16_bf16(A1, __builtin_bit_cast(v8bf, b11), acc[0][1], 0, 0, 0);
                acc[0][2] = __builtin_amdgcn_mfma_f32_32x32x16_bf16(A1, __builtin_bit_cast(v8bf, b12), acc[0][2], 0, 0, 0);
                acc[0][3] = __builtin_amdgcn_mfma_f32_32x32x16_bf16(A1, __builtin_bit_cast(v8bf, b13), acc[0][3], 0, 0, 0);
            }
            if (vh1) {
                v8bf C0 = __builtin_bit_cast(v8bf, wq[(f1 + 2 * kw) * 64 + lane]);
                v8bf C1 = __builtin_bit_cast(v8bf, wq[(f1 + 2 * kw + 1) * 64 + lane]);
                acc[1][0] = __builtin_amdgcn_mfma_f32_32x32x16_bf16(C0, __builtin_bit_cast(v8bf, b00), acc[1][0], 0, 0, 0);
                acc[1][1] = __builtin_amdgcn_mfma_f32_32x32x16_bf16(C0, __builtin_bit_cast(v8bf, b01), acc[1][1], 0, 0, 0);
                acc[1][2] = __builtin_amdgcn_mfma_f32_32x32x16_bf16(C0, __builtin_bit_cast(v8bf, b02), acc[1][2], 0, 0, 0);
                acc[1][3] = __builtin_amdgcn_mfma_f32_32x32x16_bf16(C0, __builtin_bit_cast(v8bf, b03), acc[1][3], 0, 0, 0);
                acc[1][0] = __builtin_amdgcn_mfma_f32_32x32x16_bf16(C1, __builtin_bit_cast(v8bf, b10), acc[1][0], 0, 0, 0);
                acc[1][1] = __builtin_amdgcn_mfma_f32_32x32x16_bf16(C1, __builtin_bit_cast(v8bf, b11), acc[1][1], 0, 0, 0);
                acc[1][2] = __builtin_amdgcn_mfma_f32_32x32x16_bf16(C1, __builtin_bit_cast(v8bf, b12), acc[1][2], 0, 0, 0);
                acc[1][3] = __builtin_amdgcn_mfma_f32_32x32x16_bf16(C1, __builtin_bit_cast(v8bf, b13), acc[1][3], 0, 0, 0);
            }
        }
        __builtin_amdgcn_s_setprio(0);

        // write staged row into the other buffer, then barrier
        if (r < rhi) C2_STAGE_WRITE(p ^ 1);
        __syncthreads();
    }

    // ---- epilogue: BN + hardtanh + mask ----
    const int l2 = lens1[b];
#pragma unroll
    for (int hh = 0; hh < 2; ++hh) {
        if (hh == 1 && !h1v) break;
        const int h = h0 + hh;
#pragma unroll
        for (int mt = 0; mt < 4; ++mt) {
            const int w = w0B + (wid << 7) + (mt << 5) + l31;
            const bool keep = (w < l2);
#pragma unroll
            for (int reg = 0; reg < 16; ++reg) {
                const int oc = (reg & 3) + 8 * (reg >> 2) + 4 * lhi;
                float v = fmaf(acc[hh][mt][reg], scsh[64 + oc], scsh[96 + oc]);
                v = fminf(fmaxf(v, 0.f), 20.f);
                out[(((size_t)b * C2_ + oc) * H2_ + h) * W2_ + w] = keep ? v : 0.f;
            }
        }
    }
}

// ---------------------------------------------------------------------------
extern "C" void kernel_launch(void* const* d_in, const int* in_sizes, int n_in,
                              void* d_out, int out_size, void* d_ws, size_t ws_size,
                              hipStream_t stream) {
    const float* inputs = (const float*)d_in[0];
    const int*   slen   = (const int*)d_in[1];
    const float* w1 = (const float*)d_in[2];
    const float* b1 = (const float*)d_in[3];
    const float* g1 = (const float*)d_in[4];
    const float* be1 = (const float*)d_in[5];
    const float* m1 = (const float*)d_in[6];
    const float* v1 = (const float*)d_in[7];
    const float* w2 = (const float*)d_in[8];
    const float* b2 = (const float*)d_in[9];
    const float* g2 = (const float*)d_in[10];
    const float* be2 = (const float*)d_in[11];
    const float* m2 = (const float*)d_in[12];
    const float* v2 = (const float*)d_in[13];

    char* ws = (char*)d_ws;
    unsigned short* wf2  = (unsigned short*)(ws + WF2_B);
    unsigned short* wf1  = (unsigned short*)(ws + WF1_B);
    float*          scsh = (float*)(ws + SCSH_B);
    int*            lens1 = (int*)(ws + LENS1_B);
    unsigned short* xg   = (unsigned short*)(ws + XG_B);

    float* out_x    = (float*)d_out;
    float* out_lens = out_x + OUT_X_SZ;

    hipLaunchKernelGGL(prep_kernel, dim3(256), dim3(256), 0, stream,
                       w1, b1, g1, be1, m1, v1, w2, b2, g2, be2, m2, v2,
                       slen, wf1, wf2, scsh, lens1, out_lens);

    hipLaunchKernelGGL(conv1_mfma, dim3(2, H1_, B_), dim3(256), 0, stream,
                       inputs, wf1, scsh, lens1, xg);

    // grid: 32 b * 21 h-pairs * 2 w-halves = 1344 (8*168, XCD-swizzled in-kernel)
    hipLaunchKernelGGL(conv2_mfma, dim3(1344), dim3(128), 0, stream,
                       xg, wf2, scsh, lens1, out_x);
}

// Round 3
// 564.135 us; speedup vs baseline: 1.0777x; 1.0777x over previous
//
#include <hip/hip_runtime.h>
#include <math.h>

// Problem constants
#define B_    32
#define H_IN  161
#define W_IN  1024
#define C1_   32
#define H1_   81
#define W1_   512
#define C2_   32
#define H2_   41
#define W2_   512

#define OUT_X_SZ ((size_t)B_ * C2_ * H2_ * W2_)            // 21,495,808

// ws byte offsets (all 16B-aligned)
#define WF2_B    0u            // 236544 bf16 (conv2 weights, A-frag order)
#define WF1_B    473088u       // 41*512 bf16 (conv1 weights, A-frag order, k 11->16 zero-pad)
#define SCSH_B   515072u       // 128 fp32
#define LENS1_B  515584u       // 32 int
#define XG_B     515712u       // 32*81*512*32 bf16 = 84,934,656 B

#define WF2_N    236544
#define WF1_N    20992         // 41 * 512

typedef __bf16 v8bf __attribute__((ext_vector_type(8)));
typedef float v16f __attribute__((ext_vector_type(16)));

static __device__ __forceinline__ unsigned short f2bf(float f) {
    unsigned int u = __float_as_uint(f);
    unsigned int r = (u + 0x7fffu + ((u >> 16) & 1u)) >> 16;
    return (unsigned short)r;
}

// async global->LDS 16B/lane; dest = wave-uniform LDS base + lane*16 (linear),
// source = per-lane global address. Pointer addrspace casts (NOT integer
// truncation — round-0's bug).
static __device__ __forceinline__ void gl_lds16(const void* g, void* l) {
    __builtin_amdgcn_global_load_lds(
        (const __attribute__((address_space(1))) unsigned int*)g,
        (__attribute__((address_space(3))) unsigned int*)l,
        16, 0, 0);
}

// ---------------------------------------------------------------------------
// Prep: pack conv1+conv2 weights into MFMA A-fragment lane order (bf16),
// fold BN, compute lens.
// ---------------------------------------------------------------------------
__global__ void prep_kernel(const float* __restrict__ w1, const float* __restrict__ b1,
                            const float* __restrict__ g1, const float* __restrict__ be1,
                            const float* __restrict__ m1, const float* __restrict__ v1,
                            const float* __restrict__ w2, const float* __restrict__ b2,
                            const float* __restrict__ g2, const float* __restrict__ be2,
                            const float* __restrict__ m2, const float* __restrict__ v2,
                            const int* __restrict__ lens,
                            unsigned short* __restrict__ wf1, unsigned short* __restrict__ wf2,
                            float* __restrict__ scsh, int* __restrict__ lens1,
                            float* __restrict__ out_lens)
{
    const int i = blockIdx.x * blockDim.x + threadIdx.x;
    const int stride = gridDim.x * blockDim.x;

    // wf2: frag f=(kh*11+kw)*2+ch, lane l, elem j <- w2[oc=l&31][c=ch*16+(l>>5)*8+j][kh][kw]
    for (int idx = i; idx < WF2_N; idx += stride) {
        int j  = idx & 7;
        int l  = (idx >> 3) & 63;
        int f  = idx >> 9;
        int ch = f & 1;
        int kwkh = f >> 1;
        int kw = kwkh % 11;
        int kh = kwkh / 11;
        int oc = l & 31;
        int c  = ch * 16 + ((l >> 5) << 3) + j;
        wf2[idx] = f2bf(w2[((oc * 32 + c) * 21 + kh) * 11 + kw]);
    }
    // wf1: frag kh, lane l, elem j <- w1[oc=l&31][kh][k=(l>>5)*8+j], zero for k>=11
    for (int idx = i; idx < WF1_N; idx += stride) {
        int j  = idx & 7;
        int l  = (idx >> 3) & 63;
        int kh = idx >> 9;
        int k  = ((l >> 5) << 3) + j;
        int oc = l & 31;
        wf1[idx] = (k < 11) ? f2bf(w1[oc * 451 + kh * 11 + k]) : (unsigned short)0;
    }
    if (i < 32) {
        float s1 = g1[i] / sqrtf(v1[i] + 1e-5f);
        scsh[i]      = s1;
        scsh[32 + i] = b1[i] * s1 + be1[i] - m1[i] * s1;
        float s2 = g2[i] / sqrtf(v2[i] + 1e-5f);
        scsh[64 + i] = s2;
        scsh[96 + i] = b2[i] * s2 + be2[i] - m2[i] * s2;
        int l1 = (lens[i] - 1) / 2 + 1;
        if (l1 > W1_) l1 = W1_;
        lens1[i] = l1;
        out_lens[i] = (float)l1;
    }
}

// ---------------------------------------------------------------------------
// Conv1 via bf16 MFMA implicit GEMM (unchanged this round).
// ---------------------------------------------------------------------------
__global__ __launch_bounds__(256) void conv1_mfma(
    const float* __restrict__ x,             // [32][1][161][1024]
    const unsigned short* __restrict__ wf1,  // frag-ordered
    const float* __restrict__ scsh,
    const int* __restrict__ lens1,
    unsigned short* __restrict__ xg)         // [32][81][512][32] bf16
{
    const int t    = threadIdx.x;
    const int lane = t & 63;
    const int l31  = lane & 31;
    const int lhi  = lane >> 5;
    const int wv   = t >> 6;
    const int w0   = blockIdx.x * 256;
    const int h    = blockIdx.y;
    const int b    = blockIdx.z;

    __shared__ unsigned int srow[2][264];    // 264 uints = 528 bf16 per buffer

    v16f acc0, acc1;
#pragma unroll
    for (int i = 0; i < 16; ++i) { acc0[i] = 0.f; acc1[i] = 0.f; }

    const int r0 = 2 * h - 20;
    const int cb = 2 * w0 - 5;               // global col of staged elem 0
    const float* xb = x + (size_t)b * (H_IN * W_IN);

    // dword read base for B frags: dw = wloc + 4*lhi
    const int dwbase = wv * 64 + l31 + 4 * lhi;

    // ---- prologue: stage row r0 into buffer 0 ----
    {
        float a0 = 0.f, a1 = 0.f, c0v = 0.f, c1v = 0.f;
        if (r0 >= 0 && r0 < H_IN) {
            const float* src = xb + (size_t)r0 * W_IN;
            int c0 = cb + 2 * t;
            if ((unsigned)c0 < (unsigned)W_IN)       a0 = src[c0];
            if ((unsigned)(c0 + 1) < (unsigned)W_IN) a1 = src[c0 + 1];
            if (t < 7) {
                int c1 = cb + 2 * (256 + t);
                if ((unsigned)c1 < (unsigned)W_IN)       c0v = src[c1];
                if ((unsigned)(c1 + 1) < (unsigned)W_IN) c1v = src[c1 + 1];
            }
        }
        srow[0][t] = (unsigned int)f2bf(a0) | ((unsigned int)f2bf(a1) << 16);
        if (t < 7)
            srow[0][256 + t] = (unsigned int)f2bf(c0v) | ((unsigned int)f2bf(c1v) << 16);
    }
    __syncthreads();

    for (int kh = 0; kh < 41; ++kh) {
        const int p = kh & 1;
        const int rn = r0 + kh + 1;
        const bool rv = (kh < 40) && (rn >= 0) && (rn < H_IN);

        // issue next-row staging loads (hidden under MFMAs)
        float a0 = 0.f, a1 = 0.f, c0v = 0.f, c1v = 0.f;
        if (rv) {
            const float* src = xb + (size_t)rn * W_IN;
            int c0 = cb + 2 * t;
            if ((unsigned)c0 < (unsigned)W_IN)       a0 = src[c0];
            if ((unsigned)(c0 + 1) < (unsigned)W_IN) a1 = src[c0 + 1];
            if (t < 7) {
                int c1 = cb + 2 * (256 + t);
                if ((unsigned)c1 < (unsigned)W_IN)       c0v = src[c1];
                if ((unsigned)(c1 + 1) < (unsigned)W_IN) c1v = src[c1 + 1];
            }
        }

        // compute on buffer p
        const int r = r0 + kh;
        if (r >= 0 && r < H_IN) {
            uint4 a_u = *((const uint4*)wf1 + kh * 32 + lane);
            v8bf a = __builtin_bit_cast(v8bf, a_u);
            const unsigned int* bp = &srow[p][0];
            {
                int dw = dwbase;
                uint4 bu;
                bu.x = bp[dw]; bu.y = bp[dw + 1]; bu.z = bp[dw + 2]; bu.w = bp[dw + 3];
                v8bf bb = __builtin_bit_cast(v8bf, bu);
                acc0 = __builtin_amdgcn_mfma_f32_32x32x16_bf16(a, bb, acc0, 0, 0, 0);
            }
            {
                int dw = dwbase + 32;
                uint4 bu;
                bu.x = bp[dw]; bu.y = bp[dw + 1]; bu.z = bp[dw + 2]; bu.w = bp[dw + 3];
                v8bf bb = __builtin_bit_cast(v8bf, bu);
                acc1 = __builtin_amdgcn_mfma_f32_32x32x16_bf16(a, bb, acc1, 0, 0, 0);
            }
        }

        // write staged row into buffer p^1
        if (rv) {
            srow[p ^ 1][t] = (unsigned int)f2bf(a0) | ((unsigned int)f2bf(a1) << 16);
            if (t < 7)
                srow[p ^ 1][256 + t] = (unsigned int)f2bf(c0v) | ((unsigned int)f2bf(c1v) << 16);
        }
        __syncthreads();
    }

    // ---- epilogue: BN + hardtanh + mask, write xg[b][h][w][c] bf16 ----
    const int l1 = lens1[b];
#pragma unroll
    for (int nt = 0; nt < 2; ++nt) {
        const int w = w0 + wv * 64 + nt * 32 + l31;
        const bool keep = (w < l1);
        unsigned short* dp = xg + (((size_t)b * H1_ + h) * W1_ + w) * 32;
#pragma unroll
        for (int rq = 0; rq < 4; ++rq) {
            unsigned int wd[2];
#pragma unroll
            for (int d = 0; d < 2; ++d) {
                int rg = rq * 4 + d * 2;
                int oc = 8 * rq + 4 * lhi + d * 2;
                float av0 = (nt == 0) ? acc0[rg]     : acc1[rg];
                float av1 = (nt == 0) ? acc0[rg + 1] : acc1[rg + 1];
                float v0 = fminf(fmaxf(fmaf(av0, scsh[oc],     scsh[32 + oc]), 0.f), 20.f);
                float v1 = fminf(fmaxf(fmaf(av1, scsh[oc + 1], scsh[33 + oc]), 0.f), 20.f);
                if (!keep) { v0 = 0.f; v1 = 0.f; }
                wd[d] = (unsigned int)f2bf(v0) | ((unsigned int)f2bf(v1) << 16);
            }
            uint2 u; u.x = wd[0]; u.y = wd[1];
            *(uint2*)(dp + 8 * rq + 4 * lhi) = u;
        }
    }
}

// ---------------------------------------------------------------------------
// Conv2 v5: barrier-free 1-wave blocks. Wave owns 128 w (4 m-tiles) x h-pair.
// Per input row r: vmcnt(0) [prev staging, issued a full row ago -> free],
// fix halo zeros, lgkmcnt(0), issue 9 global_load_lds for row r+1 (overlap
// this row's MFMAs), then kw loop: 8 LDS B-frag reads + 4 L2 A-frag loads
// -> 16 MFMAs. B-frag reused x2 (h-pair), A-frag reused x4 (m-tiles).
// No __syncthreads anywhere: single-wave DS-FIFO ordering + explicit waits.
//
// LDS: 2 buffers x 144 positions x 64 B = 18432 B. Position P holds
// w' = qw*128 + P - 5; 16B slot sg of a position stored at sg ^ ((P>>1)&3)
// (inverse-swizzled global SOURCE feeds the linear global_load_lds dest;
// same involution on the read side). Invalid w' chunks clamp their source
// in-bounds and the <=5 read-visible halo positions are zeroed per row by
// one predicated ds_write_b128 after vmcnt(0).
// ---------------------------------------------------------------------------
#define C2POS 144
#define C2BUF (C2POS * 64)     // 9216 B per buffer

__global__ __launch_bounds__(64, 2) void conv2_mfma(
    const unsigned short* __restrict__ xg,   // [32][81][512][32] bf16
    const unsigned short* __restrict__ wf2,  // frag-ordered
    const float* __restrict__ scsh,
    const int* __restrict__ lens1,
    float* __restrict__ out)                 // [32][32][41][512] fp32
{
    const int lane = threadIdx.x;
    const int l31  = lane & 31;
    const int lhi  = lane >> 5;

    // XCD-aware bijective swizzle: grid 2688 = 8 * 336; same-b same-hp
    // blocks cluster on one XCD so xg row re-reads hit that XCD's L2.
    const int id  = blockIdx.x;
    const int sid = (id & 7) * 336 + (id >> 3);
    const int qw  = sid & 3;                 // 128-w quarter
    const int bh  = sid >> 2;                // 0..671
    const int hp  = bh % 21;
    const int b   = bh / 21;
    const int h0  = hp << 1;
    const bool h1v = (h0 + 1) < 41;

    __shared__ __align__(16) char sbuf[2 * C2BUF];

    const int wbase = qw << 7;               // 0,128,256,384
    const unsigned short* xb = xg + (size_t)b * (H1_ * W1_ * 32);

    // r-invariant per-lane staging source offsets (bytes within an xg row).
    // LDS chunk k = i*64+lane (linear dest) pulls global slot
    // sg = (k&3) ^ swz(P) of position P = k>>2; invalid w' clamps to w'=0.
    int soff[9];
#pragma unroll
    for (int i = 0; i < 9; ++i) {
        int k  = i * 64 + lane;
        int P  = k >> 2;
        int sg = (k & 3) ^ ((P >> 1) & 3);
        int wp = wbase + P - 5;
        bool v = (wp >= 0) && (wp < W1_);
        soff[i] = (v ? wp * 64 : 0) + sg * 16;
    }
    // read-visible halo positions needing zeros: qw==0 -> P 0..4 (w'<0),
    // qw==3 -> P 133..137 (w'>=512). 5 pos x 4 slots = 20 chunks.
    const bool haszero = (qw == 0) || (qw == 3);
    const int  zoff    = (((qw == 0 ? 0 : 133) + (lane >> 2)) << 6) + ((lane & 3) << 4);

    const int rlo = max(0, 2 * h0 - 10);
    const int rhi = min(80, 2 * h0 + 12);

    v16f acc[2][4];
#pragma unroll
    for (int hh = 0; hh < 2; ++hh)
#pragma unroll
        for (int mt = 0; mt < 4; ++mt)
#pragma unroll
            for (int q = 0; q < 16; ++q) acc[hh][mt][q] = 0.f;

    // prologue: stage row rlo into buffer 0
    {
        const char* xrow = (const char*)(xb + (size_t)rlo * (W1_ * 32));
#pragma unroll
        for (int i = 0; i < 9; ++i)
            gl_lds16(xrow + soff[i], sbuf + i * 1024);
    }

    const uint4* wfq = (const uint4*)wf2;

    for (int r = rlo; r <= rhi; ++r) {
        const int p = (r - rlo) & 1;
        const char* bb = sbuf + p * C2BUF;

        // this row's staging (issued one full row ago) has landed
        asm volatile("s_waitcnt vmcnt(0)" ::: "memory");

        // overwrite clamped-garbage halo positions with zeros (DS FIFO
        // orders this before the reads below)
        if (haszero && lane < 20) {
            uint4 z; z.x = z.y = z.z = z.w = 0u;
            *(uint4*)(const_cast<char*>(bb) + zoff) = z;
        }

        // issue next-row staging into the other buffer; lgkmcnt(0) first so
        // the previous row's ds_reads of that buffer have all retired
        if (r < rhi) {
            asm volatile("s_waitcnt lgkmcnt(0)" ::: "memory");
            const char* xrow = (const char*)(xb + (size_t)(r + 1) * (W1_ * 32));
            char* db = sbuf + (p ^ 1) * C2BUF;
#pragma unroll
            for (int i = 0; i < 9; ++i)
                gl_lds16(xrow + soff[i], db + i * 1024);
        }

        const int kh0 = r + 10 - 2 * h0;     // >= 0 by rlo construction
        const int kh1 = kh0 - 2;
        const bool vh0 = (kh0 <= 20);
        const bool vh1 = h1v && (kh1 >= 0);  // kh1 <= 20 automatic
        const int f0 = kh0 * 22;
        const int f1 = kh1 * 22;

        __builtin_amdgcn_s_setprio(1);
#pragma unroll
        for (int kw = 0; kw < 11; ++kw) {
            const int P0   = l31 + kw;       // position for mt=0
            const int swz  = (P0 >> 1) & 3;
            const int a0   = (P0 << 6) + ((lhi ^ swz) << 4);     // ch=0
            const int a1   = a0 ^ 32;                            // ch=1
            uint4 b00 = *(const uint4*)(bb + a0);
            uint4 b01 = *(const uint4*)(bb + a0 + 2048);
            uint4 b02 = *(const uint4*)(bb + a0 + 4096);
            uint4 b03 = *(const uint4*)(bb + a0 + 6144);
            uint4 b10 = *(const uint4*)(bb + a1);
            uint4 b11 = *(const uint4*)(bb + a1 + 2048);
            uint4 b12 = *(const uint4*)(bb + a1 + 4096);
            uint4 b13 = *(const uint4*)(bb + a1 + 6144);
            if (vh0) {
                v8bf A0 = __builtin_bit_cast(v8bf, wfq[(f0 + 2 * kw) * 64 + lane]);
                v8bf A1 = __builtin_bit_cast(v8bf, wfq[(f0 + 2 * kw + 1) * 64 + lane]);
                acc[0][0] = __builtin_amdgcn_mfma_f32_32x32x16_bf16(A0, __builtin_bit_cast(v8bf, b00), acc[0][0], 0, 0, 0);
                acc[0][1] = __builtin_amdgcn_mfma_f32_32x32x16_bf16(A0, __builtin_bit_cast(v8bf, b01), acc[0][1], 0, 0, 0);
                acc[0][2] = __builtin_amdgcn_mfma_f32_32x32x16_bf16(A0, __builtin_bit_cast(v8bf, b02), acc[0][2], 0, 0, 0);
                acc[0][3] = __builtin_amdgcn_mfma_f32_32x32x16_bf16(A0, __builtin_bit_cast(v8bf, b03), acc[0][3], 0, 0, 0);
                acc[0][0] = __builtin_amdgcn_mfma_f32_32x32x16_bf16(A1, __builtin_bit_cast(v8bf, b10), acc[0][0], 0, 0, 0);
                acc[0][1] = __builtin_amdgcn_mfma_f32_32x32x16_bf16(A1, __builtin_bit_cast(v8bf, b11), acc[0][1], 0, 0, 0);
                acc[0][2] = __builtin_amdgcn_mfma_f32_32x32x16_bf16(A1, __builtin_bit_cast(v8bf, b12), acc[0][2], 0, 0, 0);
                acc[0][3] = __builtin_amdgcn_mfma_f32_32x32x16_bf16(A1, __builtin_bit_cast(v8bf, b13), acc[0][3], 0, 0, 0);
            }
            if (vh1) {
                v8bf C0 = __builtin_bit_cast(v8bf, wfq[(f1 + 2 * kw) * 64 + lane]);
                v8bf C1 = __builtin_bit_cast(v8bf, wfq[(f1 + 2 * kw + 1) * 64 + lane]);
                acc[1][0] = __builtin_amdgcn_mfma_f32_32x32x16_bf16(C0, __builtin_bit_cast(v8bf, b00), acc[1][0], 0, 0, 0);
                acc[1][1] = __builtin_amdgcn_mfma_f32_32x32x16_bf16(C0, __builtin_bit_cast(v8bf, b01), acc[1][1], 0, 0, 0);
                acc[1][2] = __builtin_amdgcn_mfma_f32_32x32x16_bf16(C0, __builtin_bit_cast(v8bf, b02), acc[1][2], 0, 0, 0);
                acc[1][3] = __builtin_amdgcn_mfma_f32_32x32x16_bf16(C0, __builtin_bit_cast(v8bf, b03), acc[1][3], 0, 0, 0);
                acc[1][0] = __builtin_amdgcn_mfma_f32_32x32x16_bf16(C1, __builtin_bit_cast(v8bf, b10), acc[1][0], 0, 0, 0);
                acc[1][1] = __builtin_amdgcn_mfma_f32_32x32x16_bf16(C1, __builtin_bit_cast(v8bf, b11), acc[1][1], 0, 0, 0);
                acc[1][2] = __builtin_amdgcn_mfma_f32_32x32x16_bf16(C1, __builtin_bit_cast(v8bf, b12), acc[1][2], 0, 0, 0);
                acc[1][3] = __builtin_amdgcn_mfma_f32_32x32x16_bf16(C1, __builtin_bit_cast(v8bf, b13), acc[1][3], 0, 0, 0);
            }
        }
        __builtin_amdgcn_s_setprio(0);
    }

    // ---- epilogue: BN + hardtanh + mask ----
    const int l2 = lens1[b];
#pragma unroll
    for (int hh = 0; hh < 2; ++hh) {
        if (hh == 1 && !h1v) break;
        const int h = h0 + hh;
#pragma unroll
        for (int mt = 0; mt < 4; ++mt) {
            const int w = wbase + (mt << 5) + l31;
            const bool keep = (w < l2);
#pragma unroll
            for (int reg = 0; reg < 16; ++reg) {
                const int oc = (reg & 3) + 8 * (reg >> 2) + 4 * lhi;
                float v = fmaf(acc[hh][mt][reg], scsh[64 + oc], scsh[96 + oc]);
                v = fminf(fmaxf(v, 0.f), 20.f);
                out[(((size_t)b * C2_ + oc) * H2_ + h) * W2_ + w] = keep ? v : 0.f;
            }
        }
    }
}

// ---------------------------------------------------------------------------
extern "C" void kernel_launch(void* const* d_in, const int* in_sizes, int n_in,
                              void* d_out, int out_size, void* d_ws, size_t ws_size,
                              hipStream_t stream) {
    const float* inputs = (const float*)d_in[0];
    const int*   slen   = (const int*)d_in[1];
    const float* w1 = (const float*)d_in[2];
    const float* b1 = (const float*)d_in[3];
    const float* g1 = (const float*)d_in[4];
    const float* be1 = (const float*)d_in[5];
    const float* m1 = (const float*)d_in[6];
    const float* v1 = (const float*)d_in[7];
    const float* w2 = (const float*)d_in[8];
    const float* b2 = (const float*)d_in[9];
    const float* g2 = (const float*)d_in[10];
    const float* be2 = (const float*)d_in[11];
    const float* m2 = (const float*)d_in[12];
    const float* v2 = (const float*)d_in[13];

    char* ws = (char*)d_ws;
    unsigned short* wf2  = (unsigned short*)(ws + WF2_B);
    unsigned short* wf1  = (unsigned short*)(ws + WF1_B);
    float*          scsh = (float*)(ws + SCSH_B);
    int*            lens1 = (int*)(ws + LENS1_B);
    unsigned short* xg   = (unsigned short*)(ws + XG_B);

    float* out_x    = (float*)d_out;
    float* out_lens = out_x + OUT_X_SZ;

    hipLaunchKernelGGL(prep_kernel, dim3(256), dim3(256), 0, stream,
                       w1, b1, g1, be1, m1, v1, w2, b2, g2, be2, m2, v2,
                       slen, wf1, wf2, scsh, lens1, out_lens);

    hipLaunchKernelGGL(conv1_mfma, dim3(2, H1_, B_), dim3(256), 0, stream,
                       inputs, wf1, scsh, lens1, xg);

    // grid: 32 b * 21 h-pairs * 4 w-quarters = 2688 (8*336, XCD-swizzled)
    hipLaunchKernelGGL(conv2_mfma, dim3(2688), dim3(64), 0, stream,
                       xg, wf2, scsh, lens1, out_x);
}

// Round 4
// 533.896 us; speedup vs baseline: 1.1387x; 1.0566x over previous
//
#include <hip/hip_runtime.h>
#include <math.h>

// Problem constants
#define B_    32
#define H_IN  161
#define W_IN  1024
#define C1_   32
#define H1_   81
#define W1_   512
#define C2_   32
#define H2_   41
#define W2_   512

#define OUT_X_SZ ((size_t)B_ * C2_ * H2_ * W2_)            // 21,495,808

// ws byte offsets (all 16B-aligned)
// wf2: kh padded to [-2,22] -> 25 slots x 22 frags x 512 = 281600 bf16
// wf1: kh padded to [-2,42] -> 45 slots x 512 = 23040 bf16
#define WF2_B    0u
#define WF1_B    563200u
#define SCSH_B   609280u
#define LENS1_B  609792u
#define XG_B     609920u       // 32*81*512*32 bf16 = 84,934,656 B

#define WF2_N    281600
#define WF1_N    23040

typedef __bf16 v8bf __attribute__((ext_vector_type(8)));
typedef float v16f __attribute__((ext_vector_type(16)));

static __device__ __forceinline__ unsigned short f2bf(float f) {
    unsigned int u = __float_as_uint(f);
    unsigned int r = (u + 0x7fffu + ((u >> 16) & 1u)) >> 16;
    return (unsigned short)r;
}

// ---------------------------------------------------------------------------
// Prep: pack conv1+conv2 weights into MFMA A-fragment lane order (bf16) with
// zero-padded kh halos (branch-free h-pair loops), fold BN, compute lens.
// ---------------------------------------------------------------------------
__global__ void prep_kernel(const float* __restrict__ w1, const float* __restrict__ b1,
                            const float* __restrict__ g1, const float* __restrict__ be1,
                            const float* __restrict__ m1, const float* __restrict__ v1,
                            const float* __restrict__ w2, const float* __restrict__ b2,
                            const float* __restrict__ g2, const float* __restrict__ be2,
                            const float* __restrict__ m2, const float* __restrict__ v2,
                            const int* __restrict__ lens,
                            unsigned short* __restrict__ wf1, unsigned short* __restrict__ wf2,
                            float* __restrict__ scsh, int* __restrict__ lens1,
                            float* __restrict__ out_lens)
{
    const int i = blockIdx.x * blockDim.x + threadIdx.x;
    const int stride = gridDim.x * blockDim.x;

    // wf2: frag f = khp*22 + kw*2 + ch (khp = kh+2, kh in [-2,22]),
    // lane l, elem j <- w2[oc=l&31][c=ch*16+(l>>5)*8+j][kh][kw]; zero outside
    for (int idx = i; idx < WF2_N; idx += stride) {
        int j  = idx & 7;
        int l  = (idx >> 3) & 63;
        int f  = idx >> 9;
        int ch = f & 1;
        int kwkh = f >> 1;
        int kw  = kwkh % 11;
        int khp = kwkh / 11;           // 0..24
        int kh  = khp - 2;
        int oc = l & 31;
        int c  = ch * 16 + ((l >> 5) << 3) + j;
        wf2[idx] = (kh >= 0 && kh < 21)
                 ? f2bf(w2[((oc * 32 + c) * 21 + kh) * 11 + kw]) : (unsigned short)0;
    }
    // wf1: frag khp = kh+2 (kh in [-2,42]), lane l, elem j <-
    // w1[oc=l&31][kh][k=(l>>5)*8+j]; zero for k>=11 or kh outside [0,41)
    for (int idx = i; idx < WF1_N; idx += stride) {
        int j   = idx & 7;
        int l   = (idx >> 3) & 63;
        int khp = idx >> 9;            // 0..44
        int kh  = khp - 2;
        int k   = ((l >> 5) << 3) + j;
        int oc  = l & 31;
        wf1[idx] = (k < 11 && kh >= 0 && kh < 41)
                 ? f2bf(w1[oc * 451 + kh * 11 + k]) : (unsigned short)0;
    }
    if (i < 32) {
        float s1 = g1[i] / sqrtf(v1[i] + 1e-5f);
        scsh[i]      = s1;
        scsh[32 + i] = b1[i] * s1 + be1[i] - m1[i] * s1;
        float s2 = g2[i] / sqrtf(v2[i] + 1e-5f);
        scsh[64 + i] = s2;
        scsh[96 + i] = b2[i] * s2 + be2[i] - m2[i] * s2;
        int l1 = (lens[i] - 1) / 2 + 1;
        if (l1 > W1_) l1 = W1_;
        lens1[i] = l1;
        out_lens[i] = (float)l1;
    }
}

// ---------------------------------------------------------------------------
// Conv1 v6: h-pair MFMA implicit GEMM. Block (w-half 256, h-pair, b), 4 waves.
// Loop input rows r = 2h0-20 .. 2h0+22 (43 iters); per row ONE staged 528-col
// slab feeds BOTH h0 (kh=kh') and h1 (kh=kh'-2) via zero-padded wf1 —
// branch-free, 4 MFMAs per stage (was 2), staging per output halved.
// ---------------------------------------------------------------------------
__global__ __launch_bounds__(256) void conv1_mfma(
    const float* __restrict__ x,             // [32][1][161][1024]
    const unsigned short* __restrict__ wf1,  // frag-ordered, kh-padded (45)
    const float* __restrict__ scsh,
    const int* __restrict__ lens1,
    unsigned short* __restrict__ xg)         // [32][81][512][32] bf16
{
    const int t    = threadIdx.x;
    const int lane = t & 63;
    const int l31  = lane & 31;
    const int lhi  = lane >> 5;
    const int wv   = t >> 6;
    const int w0   = blockIdx.x * 256;
    const int hp   = blockIdx.y;
    const int b    = blockIdx.z;
    const int h0   = hp * 2;
    const bool h1ok = (h0 + 1) < H1_;

    __shared__ unsigned int srow[2][264];    // 264 uints = 528 bf16 per buffer

    v16f acc[2][2];
#pragma unroll
    for (int hh = 0; hh < 2; ++hh)
#pragma unroll
        for (int nt = 0; nt < 2; ++nt)
#pragma unroll
            for (int q = 0; q < 16; ++q) acc[hh][nt][q] = 0.f;

    const int r0 = 2 * h0 - 20;
    const int cb = 2 * w0 - 5;               // global col of staged elem 0
    const float* xb = x + (size_t)b * (H_IN * W_IN);

    // dword read base for B frags: dw = n + 4*lhi, n = wv*64 + l31 (+32 nt1)
    const int dwbase = wv * 64 + l31 + 4 * lhi;

    // ---- prologue: stage row r0 into buffer 0 (zeros when OOB) ----
    {
        float a0 = 0.f, a1 = 0.f, c0v = 0.f, c1v = 0.f;
        if (r0 >= 0 && r0 < H_IN) {
            const float* src = xb + (size_t)r0 * W_IN;
            int c0 = cb + 2 * t;
            if ((unsigned)c0 < (unsigned)W_IN)       a0 = src[c0];
            if ((unsigned)(c0 + 1) < (unsigned)W_IN) a1 = src[c0 + 1];
            if (t < 7) {
                int c1 = cb + 2 * (256 + t);
                if ((unsigned)c1 < (unsigned)W_IN)       c0v = src[c1];
                if ((unsigned)(c1 + 1) < (unsigned)W_IN) c1v = src[c1 + 1];
            }
        }
        srow[0][t] = (unsigned int)f2bf(a0) | ((unsigned int)f2bf(a1) << 16);
        if (t < 7)
            srow[0][256 + t] = (unsigned int)f2bf(c0v) | ((unsigned int)f2bf(c1v) << 16);
    }
    __syncthreads();

    const uint4* wf1q = (const uint4*)wf1;

    for (int kp = 0; kp < 43; ++kp) {
        const int p = kp & 1;
        const int rn = r0 + kp + 1;
        const bool rv = (kp < 42) && (rn >= 0) && (rn < H_IN);

        // issue next-row staging loads (hidden under MFMAs)
        float a0 = 0.f, a1 = 0.f, c0v = 0.f, c1v = 0.f;
        if (rv) {
            const float* src = xb + (size_t)rn * W_IN;
            int c0 = cb + 2 * t;
            if ((unsigned)c0 < (unsigned)W_IN)       a0 = src[c0];
            if ((unsigned)(c0 + 1) < (unsigned)W_IN) a1 = src[c0 + 1];
            if (t < 7) {
                int c1 = cb + 2 * (256 + t);
                if ((unsigned)c1 < (unsigned)W_IN)       c0v = src[c1];
                if ((unsigned)(c1 + 1) < (unsigned)W_IN) c1v = src[c1 + 1];
            }
        }

        // compute on buffer p: row r serves h0 (kh=kp, khp0=kp+2) and
        // h1 (kh=kp-2, khp1=kp) — both always valid via zero-padded wf1
        const int r = r0 + kp;
        if (r >= 0 && r < H_IN) {
            uint4 a0u = wf1q[(kp + 2) * 32 + lane];
            uint4 a1u = wf1q[kp * 32 + lane];
            v8bf A0 = __builtin_bit_cast(v8bf, a0u);
            v8bf A1 = __builtin_bit_cast(v8bf, a1u);
            const unsigned int* bp = &srow[p][0];
            uint4 bu0, bu1;
            {
                int dw = dwbase;
                bu0.x = bp[dw]; bu0.y = bp[dw + 1]; bu0.z = bp[dw + 2]; bu0.w = bp[dw + 3];
                dw += 32;
                bu1.x = bp[dw]; bu1.y = bp[dw + 1]; bu1.z = bp[dw + 2]; bu1.w = bp[dw + 3];
            }
            v8bf B0 = __builtin_bit_cast(v8bf, bu0);
            v8bf B1 = __builtin_bit_cast(v8bf, bu1);
            acc[0][0] = __builtin_amdgcn_mfma_f32_32x32x16_bf16(A0, B0, acc[0][0], 0, 0, 0);
            acc[0][1] = __builtin_amdgcn_mfma_f32_32x32x16_bf16(A0, B1, acc[0][1], 0, 0, 0);
            acc[1][0] = __builtin_amdgcn_mfma_f32_32x32x16_bf16(A1, B0, acc[1][0], 0, 0, 0);
            acc[1][1] = __builtin_amdgcn_mfma_f32_32x32x16_bf16(A1, B1, acc[1][1], 0, 0, 0);
        }

        // write staged row into buffer p^1
        if (rv) {
            srow[p ^ 1][t] = (unsigned int)f2bf(a0) | ((unsigned int)f2bf(a1) << 16);
            if (t < 7)
                srow[p ^ 1][256 + t] = (unsigned int)f2bf(c0v) | ((unsigned int)f2bf(c1v) << 16);
        }
        __syncthreads();
    }

    // ---- epilogue: BN + hardtanh + mask, write xg[b][h][w][c] bf16 ----
    const int l1 = lens1[b];
#pragma unroll
    for (int hh = 0; hh < 2; ++hh) {
        if (hh == 1 && !h1ok) break;
        const int h = h0 + hh;
#pragma unroll
        for (int nt = 0; nt < 2; ++nt) {
            const int w = w0 + wv * 64 + nt * 32 + l31;
            const bool keep = (w < l1);
            unsigned short* dp = xg + (((size_t)b * H1_ + h) * W1_ + w) * 32;
#pragma unroll
            for (int rq = 0; rq < 4; ++rq) {
                unsigned int wd[2];
#pragma unroll
                for (int d = 0; d < 2; ++d) {
                    int rg = rq * 4 + d * 2;
                    int oc = 8 * rq + 4 * lhi + d * 2;
                    float av0 = acc[hh][nt][rg];
                    float av1 = acc[hh][nt][rg + 1];
                    float v0 = fminf(fmaxf(fmaf(av0, scsh[oc],     scsh[32 + oc]), 0.f), 20.f);
                    float v1 = fminf(fmaxf(fmaf(av1, scsh[oc + 1], scsh[33 + oc]), 0.f), 20.f);
                    if (!keep) { v0 = 0.f; v1 = 0.f; }
                    wd[d] = (unsigned int)f2bf(v0) | ((unsigned int)f2bf(v1) << 16);
                }
                uint2 u; u.x = wd[0]; u.y = wd[1];
                *(uint2*)(dp + 8 * rq + 4 * lhi) = u;
            }
        }
    }
}

// ---------------------------------------------------------------------------
// Conv2 v6: the proven 340-µs structure (4-wave block, 80B-stride LDS row,
// reg-staged rows, one barrier/row) + h-pair register reuse + branch-free
// zero-padded kh + bijective XCD swizzle. Per row r = 2h0-10+kp (23 iters):
// stage row once, each wave does 11kw x 2ch x {2 A-frags (kh0=kp, kh1=kp-2,
// padded), 2 B-frags} -> 88 MFMAs. B-frag feeds 2 MFMAs (512 B/MFMA LDS).
// ---------------------------------------------------------------------------
#define ROWB 21280   // 266 positions * 80 B (64 data + 16 pad: conflict-light)

__global__ __launch_bounds__(256, 3) void conv2_mfma(
    const unsigned short* __restrict__ xg,   // [32][81][512][32] bf16
    const unsigned short* __restrict__ wf2,  // frag-ordered, kh-padded (25)
    const float* __restrict__ scsh,
    const int* __restrict__ lens1,
    float* __restrict__ out)                 // [32][32][41][512] fp32
{
    const int t    = threadIdx.x;
    const int lane = t & 63;
    const int l31  = lane & 31;
    const int lhi  = lane >> 5;
    const int wv   = t >> 6;

    // bijective XCD swizzle: grid 1344 = 8 * 168; same-b blocks cluster on
    // one XCD so overlapping xg-row reads hit that XCD's L2.
    const int id   = blockIdx.x;
    const int sid  = (id & 7) * 168 + (id >> 3);
    const int wblk = sid & 1;
    const int bh   = sid >> 1;               // 0..671
    const int hp   = bh % 21;
    const int b    = bh / 21;
    const int h0   = hp * 2;
    const bool h1ok = (h0 + 1) < H2_;
    const int w0B  = wblk << 8;

    __shared__ __align__(16) char sbuf[2 * ROWB];

    v16f acc[2][2];
#pragma unroll
    for (int hh = 0; hh < 2; ++hh)
#pragma unroll
        for (int nt = 0; nt < 2; ++nt)
#pragma unroll
            for (int q = 0; q < 16; ++q) acc[hh][nt][q] = 0.f;

    const int st_lds = (t >> 2) * 80 + (t & 3) * 16;
    const int rd_lds = (wv * 64 + l31) * 80 + lhi * 16;

    const unsigned short* xb = xg + (size_t)b * (H1_ * W1_ * 32);
    const int r0 = 2 * h0 - 10;

    // ---- prologue: stage row r0 into buffer 0 ----
    {
        int r = r0;
        if (r >= 0 && r < H1_) {
            const unsigned short* xrow = xb + (size_t)r * (W1_ * 32);
#pragma unroll
            for (int it = 0; it < 5; ++it) {
                int i = t + it * 256;
                int wp = (i >> 2) + w0B - 5;
                uint4 z; z.x = z.y = z.z = z.w = 0u;
                if (i < 1064 && wp >= 0 && wp < W1_)
                    z = *(const uint4*)(xrow + (size_t)wp * 32 + (i & 3) * 8);
                if (i < 1064)
                    *(uint4*)(sbuf + st_lds + it * 5120) = z;
            }
        }
    }
    __syncthreads();

    const uint4* wq = (const uint4*)wf2;

    for (int kp = 0; kp < 23; ++kp) {
        const int p = kp & 1;
        const int rn = r0 + kp + 1;
        const bool stage_next = (kp < 22) && (rn >= 0) && (rn < H1_);

        uint4 g0, g1, g2, g3, g4;
        g0.x=g0.y=g0.z=g0.w=0u; g1=g0; g2=g0; g3=g0; g4=g0;
        if (stage_next) {
            const unsigned short* xrow = xb + (size_t)rn * (W1_ * 32);
            const int wbase = (t >> 2) + w0B - 5;
            const int ck = (t & 3) * 8;
            if (wbase >= 0 && wbase < W1_)                 g0 = *(const uint4*)(xrow + (size_t)wbase * 32 + ck);
            if (wbase + 64 >= 0 && wbase + 64 < W1_)       g1 = *(const uint4*)(xrow + (size_t)(wbase + 64) * 32 + ck);
            if (wbase + 128 < W1_)                         g2 = *(const uint4*)(xrow + (size_t)(wbase + 128) * 32 + ck);
            if (wbase + 192 < W1_)                         g3 = *(const uint4*)(xrow + (size_t)(wbase + 192) * 32 + ck);
            if (t < 40 && wbase + 256 < W1_)               g4 = *(const uint4*)(xrow + (size_t)(wbase + 256) * 32 + ck);
        }

        const int r = r0 + kp;
        if (r >= 0 && r < H1_) {
            // h0: kh = kp (khp0 = kp+2); h1: kh = kp-2 (khp1 = kp).
            // Both always "valid" via zero-padded weights — branch-free body.
            const int f0 = (kp + 2) * 22;
            const int f1 = kp * 22;
            const char* bbase = sbuf + p * ROWB + rd_lds;
            __builtin_amdgcn_s_setprio(1);
#pragma unroll
            for (int kw = 0; kw < 11; ++kw) {
#pragma unroll
                for (int ch = 0; ch < 2; ++ch) {
                    uint4 a0u = wq[(f0 + kw * 2 + ch) * 64 + lane];
                    uint4 a1u = wq[(f1 + kw * 2 + ch) * 64 + lane];
                    uint4 b0u = *(const uint4*)(bbase + kw * 80 + ch * 32);
                    uint4 b1u = *(const uint4*)(bbase + 2560 + kw * 80 + ch * 32);
                    v8bf A0 = __builtin_bit_cast(v8bf, a0u);
                    v8bf A1 = __builtin_bit_cast(v8bf, a1u);
                    v8bf B0 = __builtin_bit_cast(v8bf, b0u);
                    v8bf B1 = __builtin_bit_cast(v8bf, b1u);
                    acc[0][0] = __builtin_amdgcn_mfma_f32_32x32x16_bf16(A0, B0, acc[0][0], 0, 0, 0);
                    acc[0][1] = __builtin_amdgcn_mfma_f32_32x32x16_bf16(A0, B1, acc[0][1], 0, 0, 0);
                    acc[1][0] = __builtin_amdgcn_mfma_f32_32x32x16_bf16(A1, B0, acc[1][0], 0, 0, 0);
                    acc[1][1] = __builtin_amdgcn_mfma_f32_32x32x16_bf16(A1, B1, acc[1][1], 0, 0, 0);
                }
            }
            __builtin_amdgcn_s_setprio(0);
        }

        if (stage_next) {
            char* wb = sbuf + (p ^ 1) * ROWB + st_lds;
            *(uint4*)(wb)            = g0;
            *(uint4*)(wb + 5120)     = g1;
            *(uint4*)(wb + 2 * 5120) = g2;
            *(uint4*)(wb + 3 * 5120) = g3;
            if (t < 40) *(uint4*)(wb + 4 * 5120) = g4;
        }
        __syncthreads();
    }

    // ---- epilogue: BN + hardtanh + mask ----
    const int l2 = lens1[b];
#pragma unroll
    for (int hh = 0; hh < 2; ++hh) {
        if (hh == 1 && !h1ok) break;
        const int h = h0 + hh;
#pragma unroll
        for (int nt = 0; nt < 2; ++nt) {
            const int w = w0B + wv * 64 + nt * 32 + l31;
            const bool keep = (w < l2);
#pragma unroll
            for (int reg = 0; reg < 16; ++reg) {
                const int oc = (reg & 3) + 8 * (reg >> 2) + 4 * lhi;
                float v = fmaf(acc[hh][nt][reg], scsh[64 + oc], scsh[96 + oc]);
                v = fminf(fmaxf(v, 0.f), 20.f);
                out[(((size_t)b * C2_ + oc) * H2_ + h) * W2_ + w] = keep ? v : 0.f;
            }
        }
    }
}

// ---------------------------------------------------------------------------
extern "C" void kernel_launch(void* const* d_in, const int* in_sizes, int n_in,
                              void* d_out, int out_size, void* d_ws, size_t ws_size,
                              hipStream_t stream) {
    const float* inputs = (const float*)d_in[0];
    const int*   slen   = (const int*)d_in[1];
    const float* w1 = (const float*)d_in[2];
    const float* b1 = (const float*)d_in[3];
    const float* g1 = (const float*)d_in[4];
    const float* be1 = (const float*)d_in[5];
    const float* m1 = (const float*)d_in[6];
    const float* v1 = (const float*)d_in[7];
    const float* w2 = (const float*)d_in[8];
    const float* b2 = (const float*)d_in[9];
    const float* g2 = (const float*)d_in[10];
    const float* be2 = (const float*)d_in[11];
    const float* m2 = (const float*)d_in[12];
    const float* v2 = (const float*)d_in[13];

    char* ws = (char*)d_ws;
    unsigned short* wf2  = (unsigned short*)(ws + WF2_B);
    unsigned short* wf1  = (unsigned short*)(ws + WF1_B);
    float*          scsh = (float*)(ws + SCSH_B);
    int*            lens1 = (int*)(ws + LENS1_B);
    unsigned short* xg   = (unsigned short*)(ws + XG_B);

    float* out_x    = (float*)d_out;
    float* out_lens = out_x + OUT_X_SZ;

    hipLaunchKernelGGL(prep_kernel, dim3(256), dim3(256), 0, stream,
                       w1, b1, g1, be1, m1, v1, w2, b2, g2, be2, m2, v2,
                       slen, wf1, wf2, scsh, lens1, out_lens);

    // conv1: 2 w-halves x 41 h-pairs x 32 b (h-pair: covers h 0..80, last pair partial)
    hipLaunchKernelGGL(conv1_mfma, dim3(2, 41, B_), dim3(256), 0, stream,
                       inputs, wf1, scsh, lens1, xg);

    // conv2: 32 b * 21 h-pairs * 2 w-halves = 1344 (8*168, XCD-swizzled in-kernel)
    hipLaunchKernelGGL(conv2_mfma, dim3(1344), dim3(256), 0, stream,
                       xg, wf2, scsh, lens1, out_x);
}